// Round 7
// baseline (291.099 us; speedup 1.0000x reference)
//
#include <hip/hip_runtime.h>

#define IN1 128
#define K1 256
#define HID 64
#define MCH 16    // mean-reduction chunks per graph
#define BM1 128   // gemm rows per block

typedef __attribute__((ext_vector_type(8))) __bf16 bf16x8;
typedef __attribute__((ext_vector_type(4))) __bf16 bf16x4;
typedef __attribute__((ext_vector_type(8))) unsigned short u16x8;
typedef __attribute__((ext_vector_type(4))) float f32x4;

// swizzled element index: XOR row-low-bits into 16B-slot bits
__device__ __forceinline__ int swz(int row, int k, int ldk) {
    return (row * ldk + k) ^ ((row & 7) << 3);
}

// ---------------- CSR build ----------------
__global__ __launch_bounds__(256) void count_edges(const int* __restrict__ ei, int* counts, int E) {
    int e = blockIdx.x * 256 + threadIdx.x;
    if (e < E) atomicAdd(&counts[ei[E + e]], 1);
}

// per-block sum of counts + dinv = rsqrt(deg+1)
__global__ __launch_bounds__(256) void block_sums_dinv(const int* __restrict__ counts,
                                                       int* __restrict__ bsum,
                                                       float* __restrict__ dinv, int N) {
    __shared__ int sh[256];
    int i = blockIdx.x * 256 + threadIdx.x;
    int v = (i < N) ? counts[i] : 0;
    if (i < N) dinv[i] = rsqrtf((float)v + 1.0f);
    sh[threadIdx.x] = v;
    __syncthreads();
    for (int off = 128; off > 0; off >>= 1) {
        if (threadIdx.x < off) sh[threadIdx.x] += sh[threadIdx.x + off];
        __syncthreads();
    }
    if (threadIdx.x == 0) bsum[blockIdx.x] = sh[0];
}

// block 0: exclusive-scan bsum[nb] -> boff[nb]; block 1: segment starts
__global__ __launch_bounds__(512) void scan_and_segs(const int* __restrict__ bsum,
                                                     int* __restrict__ boff, int nb,
                                                     const int* __restrict__ batch,
                                                     int* __restrict__ segs, int N, int B) {
    if (blockIdx.x == 0) {
        __shared__ int sh[512];
        int t = threadIdx.x;
        int v = (t < nb) ? bsum[t] : 0;
        sh[t] = v;
        __syncthreads();
        for (int off = 1; off < 512; off <<= 1) {
            int u = (t >= off) ? sh[t - off] : 0;
            __syncthreads();
            sh[t] += u;
            __syncthreads();
        }
        if (t < nb) boff[t] = sh[t] - v;
    } else {
        int b = threadIdx.x;
        if (b > B) return;
        if (b == B) { segs[B] = N; return; }
        int lo = 0, hi = N;
        while (lo < hi) {
            int mid = (lo + hi) >> 1;
            if (batch[mid] < b) lo = mid + 1; else hi = mid;
        }
        segs[b] = lo;
    }
}

__global__ __launch_bounds__(256) void write_rowstart(const int* __restrict__ counts,
                                                      const int* __restrict__ boff,
                                                      int* __restrict__ rowstart, int N, int E) {
    __shared__ int sh[256];
    int i = blockIdx.x * 256 + threadIdx.x;
    int t = threadIdx.x;
    int v = (i < N) ? counts[i] : 0;
    sh[t] = v;
    __syncthreads();
    for (int off = 1; off < 256; off <<= 1) {
        int u = (t >= off) ? sh[t - off] : 0;
        __syncthreads();
        sh[t] += u;
        __syncthreads();
    }
    if (i < N) rowstart[i] = boff[blockIdx.x] + sh[t] - v;
    if (i == 0) rowstart[N] = E;
}

__global__ __launch_bounds__(256) void scatter_csr(const int* __restrict__ ei,
                                                   const int* __restrict__ rowstart,
                                                   const float* __restrict__ dinv,
                                                   int* counts,
                                                   int* __restrict__ csr_src,
                                                   float* __restrict__ csr_w, int E) {
    int e = blockIdx.x * 256 + threadIdx.x;
    if (e >= E) return;
    int s = ei[e], d = ei[E + e];
    int pos = rowstart[d] + atomicSub(&counts[d], 1) - 1;
    csr_src[pos] = s;
    csr_w[pos] = dinv[s];
}

// ---------------- W prep: bf16, transposed, pre-swizzled images ----------------
__global__ __launch_bounds__(256) void prep_w(const float* __restrict__ W1,
                                              const float* __restrict__ W2,
                                              __bf16* __restrict__ w1img,
                                              __bf16* __restrict__ w2img) {
    int tid = blockIdx.x * 256 + threadIdx.x;
    if (tid < 64 * K1) {
        int k = tid >> 6, n = tid & 63;
        w1img[swz(n, k, K1)] = (__bf16)W1[tid];
    } else if (tid < 64 * K1 + 64 * 64) {
        int e = tid - 64 * K1;
        int k = e >> 6, n = e & 63;
        w2img[swz(n, k, 64)] = (__bf16)W2[e];
    }
}

// ---------------- MFMA GEMM 1: h1 = bf16(concat(x,xda) @ W1) ----------------
// 128 rows x 64 cols per block; 4 waves x 2 row-groups; all 16 A-loads hoisted.
__global__ __launch_bounds__(256) void gemm1_mfma(const float* __restrict__ x,
                                                  const float* __restrict__ xda,
                                                  const __bf16* __restrict__ w1img,
                                                  __bf16* __restrict__ h1, int N) {
    __shared__ __bf16 Ws[64 * K1];   // 32 KB
    int tid = threadIdx.x;
#pragma unroll
    for (int i = 0; i < 8; ++i)
        reinterpret_cast<bf16x8*>(Ws)[i * 256 + tid] =
            reinterpret_cast<const bf16x8*>(w1img)[i * 256 + tid];
    __syncthreads();

    int w = tid >> 6, l = tid & 63;
    int lr = l & 15, lg = l >> 4;
    int rbase = blockIdx.x * BM1 + w * 32;
    const float4 z4 = make_float4(0.f, 0.f, 0.f, 0.f);
    f32x4 acc[2][4] = {};
    float4 ax[2][8];

#pragma unroll
    for (int half = 0; half < 2; ++half) {
        const float* base = half ? xda : x;
        // hoist all 16 loads (8 per row-group) for this half
#pragma unroll
        for (int g = 0; g < 2; ++g) {
            int arow = rbase + g * 16 + lr;
            bool ok = arow < N;
            const float4* p = reinterpret_cast<const float4*>(base + (size_t)arow * IN1);
#pragma unroll
            for (int t = 0; t < 4; ++t) {
                ax[g][2 * t]     = ok ? p[t * 8 + lg * 2]     : z4;
                ax[g][2 * t + 1] = ok ? p[t * 8 + lg * 2 + 1] : z4;
            }
        }
#pragma unroll
        for (int t = 0; t < 4; ++t) {
            int k0 = half * 128 + t * 32 + lg * 8;
            bf16x8 bfr[4];
#pragma unroll
            for (int c = 0; c < 4; ++c)
                bfr[c] = *reinterpret_cast<const bf16x8*>(&Ws[swz(c * 16 + lr, k0, K1)]);
#pragma unroll
            for (int g = 0; g < 2; ++g) {
                float4 fa = ax[g][2 * t], fb = ax[g][2 * t + 1];
                bf16x8 af;
                af[0] = (__bf16)fa.x; af[1] = (__bf16)fa.y;
                af[2] = (__bf16)fa.z; af[3] = (__bf16)fa.w;
                af[4] = (__bf16)fb.x; af[5] = (__bf16)fb.y;
                af[6] = (__bf16)fb.z; af[7] = (__bf16)fb.w;
#pragma unroll
                for (int c = 0; c < 4; ++c)
                    acc[g][c] = __builtin_amdgcn_mfma_f32_16x16x32_bf16(af, bfr[c], acc[g][c], 0, 0, 0);
            }
        }
    }
    // C layout: col = lane&15, row = (lane>>4)*4 + reg
#pragma unroll
    for (int g = 0; g < 2; ++g)
#pragma unroll
        for (int c = 0; c < 4; ++c)
#pragma unroll
            for (int r = 0; r < 4; ++r) {
                int row = rbase + g * 16 + lg * 4 + r;
                if (row < N) h1[(size_t)row * HID + c * 16 + lr] = (__bf16)acc[g][c][r];
            }
}

// ---------------- MFMA GEMM 2: h2 = bf16(relu(x2) @ W2[0:64] + rb2[batch]) ----------------
__global__ __launch_bounds__(256) void gemm2_mfma(const __bf16* __restrict__ x2,
                                                  const __bf16* __restrict__ w2img,
                                                  const float* __restrict__ rb2,
                                                  const int* __restrict__ batch,
                                                  __bf16* __restrict__ h2, int N) {
    __shared__ __bf16 Ws[64 * 64];   // 8 KB
    int tid = threadIdx.x;
#pragma unroll
    for (int i = 0; i < 2; ++i)
        reinterpret_cast<bf16x8*>(Ws)[i * 256 + tid] =
            reinterpret_cast<const bf16x8*>(w2img)[i * 256 + tid];
    __syncthreads();

    int w = tid >> 6, l = tid & 63;
    int lr = l & 15, lg = l >> 4;
    int rbase = blockIdx.x * BM1 + w * 32;
    f32x4 acc[2][4] = {};
#pragma unroll
    for (int t = 0; t < 2; ++t) {
        int k0 = t * 32 + lg * 8;
        bf16x8 bfr[4];
#pragma unroll
        for (int c = 0; c < 4; ++c)
            bfr[c] = *reinterpret_cast<const bf16x8*>(&Ws[swz(c * 16 + lr, k0, 64)]);
#pragma unroll
        for (int g = 0; g < 2; ++g) {
            int arow = rbase + g * 16 + lr;
            u16x8 rel = {};
            if (arow < N) {
                u16x8 raw = *reinterpret_cast<const u16x8*>(x2 + (size_t)arow * HID + k0);
#pragma unroll
                for (int i = 0; i < 8; ++i)
                    rel[i] = (raw[i] & 0x8000) ? (unsigned short)0 : raw[i];   // relu on bf16
            }
            bf16x8 af = *reinterpret_cast<bf16x8*>(&rel);
#pragma unroll
            for (int c = 0; c < 4; ++c)
                acc[g][c] = __builtin_amdgcn_mfma_f32_16x16x32_bf16(af, bfr[c], acc[g][c], 0, 0, 0);
        }
    }
#pragma unroll
    for (int g = 0; g < 2; ++g)
#pragma unroll
        for (int r = 0; r < 4; ++r) {
            int row = rbase + g * 16 + lg * 4 + r;
            if (row >= N) continue;
            int b = batch[row];
            const float* rv = rb2 + (size_t)b * HID;
#pragma unroll
            for (int c = 0; c < 4; ++c)
                h2[(size_t)row * HID + c * 16 + lr] = (__bf16)(acc[g][c][r] + rv[c * 16 + lr]);
        }
}

// ---------------- gather: out = bf16( h*dinv^2 + bias + sum_e h[src]*w*dinv ) ----------------
__global__ __launch_bounds__(256) void gather(const int* __restrict__ rowstart,
                                              const int* __restrict__ csr_src,
                                              const float* __restrict__ csr_w,
                                              const __bf16* __restrict__ h,
                                              const float* __restrict__ dinv,
                                              const float* __restrict__ bias,
                                              __bf16* __restrict__ out, int N) {
    int t = blockIdx.x * 256 + threadIdx.x;
    int i = t >> 4, c = t & 15;
    if (i >= N) return;
    float di = dinv[i];
    float s2 = di * di;
    bf16x4 hv = *reinterpret_cast<const bf16x4*>(h + (size_t)i * HID + c * 4);
    float4 bv = reinterpret_cast<const float4*>(bias)[c];
    float a0 = fmaf((float)hv[0], s2, bv.x);
    float a1 = fmaf((float)hv[1], s2, bv.y);
    float a2 = fmaf((float)hv[2], s2, bv.z);
    float a3 = fmaf((float)hv[3], s2, bv.w);
    int k0 = rowstart[i], k1 = rowstart[i + 1];
    for (int k = k0; k < k1; ++k) {
        int s = csr_src[k];
        float wgt = csr_w[k] * di;
        bf16x4 sv = *reinterpret_cast<const bf16x4*>(h + (size_t)s * HID + c * 4);
        a0 = fmaf((float)sv[0], wgt, a0);
        a1 = fmaf((float)sv[1], wgt, a1);
        a2 = fmaf((float)sv[2], wgt, a2);
        a3 = fmaf((float)sv[3], wgt, a3);
    }
    bf16x4 o;
    o[0] = (__bf16)a0; o[1] = (__bf16)a1; o[2] = (__bf16)a2; o[3] = (__bf16)a3;
    *reinterpret_cast<bf16x4*>(out + (size_t)i * HID + c * 4) = o;
}

// rb2[b][j] = sum_k relu(x0[root_b][k]) * W2[64+k][j]   (fp32)
__global__ __launch_bounds__(64) void rb2_k(const float* __restrict__ x,
                                            const float* __restrict__ xda,
                                            const int* __restrict__ rootindex,
                                            const float* __restrict__ W2,
                                            float* __restrict__ rb2) {
    int b = blockIdx.x;
    int j = threadIdx.x;
    int root = rootindex[b];
    const float* xr = x + (size_t)root * IN1;
    const float* dr = xda + (size_t)root * IN1;
    float acc = 0.f;
    for (int k = 0; k < IN1; ++k) {
        float v = fmaxf(xr[k], 0.f);
        acc = fmaf(v, W2[(size_t)(HID + k) * HID + j], acc);
    }
    for (int k = 0; k < IN1; ++k) {
        float v = fmaxf(dr[k], 0.f);
        acc = fmaf(v, W2[(size_t)(HID + IN1 + k) * HID + j], acc);
    }
    rb2[b * HID + j] = acc;
}

// ---------------- mean: two-stage ----------------
__global__ __launch_bounds__(256) void mean_part(const __bf16* __restrict__ agg2,
                                                 const int* __restrict__ segs,
                                                 float* __restrict__ part) {
    int b = blockIdx.x / MCH, c = blockIdx.x % MCH;
    int s = segs[b], e = segs[b + 1];
    long len = e - s;
    int cs = s + (int)(len * c / MCH);
    int ce = s + (int)(len * (c + 1) / MCH);
    int f = threadIdx.x & 63, g = threadIdx.x >> 6;
    float p = 0.f;
    for (int i = cs + g; i < ce; i += 4)
        p += fmaxf((float)agg2[(size_t)i * HID + f], 0.f);
    __shared__ float red[4][64];
    red[g][f] = p;
    __syncthreads();
    if (g == 0)
        part[((size_t)b * MCH + c) * 64 + f] = red[0][f] + red[1][f] + red[2][f] + red[3][f];
}

__global__ __launch_bounds__(128) void mean_fin(const float* __restrict__ part,
                                                const __bf16* __restrict__ x2,
                                                const int* __restrict__ segs,
                                                const int* __restrict__ rootindex,
                                                float* __restrict__ out) {
    int b = blockIdx.x;
    int f = threadIdx.x;   // 0..127
    if (f < 64) {
        float s = 0.f;
#pragma unroll
        for (int c = 0; c < MCH; ++c) s += part[((size_t)b * MCH + c) * 64 + f];
        out[b * 128 + f] = s / (float)(segs[b + 1] - segs[b]);
    } else {
        int root = rootindex[b];
        out[b * 128 + f] = (float)x2[(size_t)root * HID + (f - 64)];
    }
}

extern "C" void kernel_launch(void* const* d_in, const int* in_sizes, int n_in,
                              void* d_out, int out_size, void* d_ws, size_t ws_size,
                              hipStream_t stream) {
    const float* x    = (const float*)d_in[0];
    const float* xda  = (const float*)d_in[1];
    const int*   ei   = (const int*)d_in[2];
    const int*   batch= (const int*)d_in[3];
    const int*   root = (const int*)d_in[4];
    const float* W1   = (const float*)d_in[5];
    const float* b1   = (const float*)d_in[6];
    const float* W2   = (const float*)d_in[7];
    const float* b2   = (const float*)d_in[8];
    float* out = (float*)d_out;

    int N = in_sizes[3];
    int E = in_sizes[2] / 2;
    int B = in_sizes[4];

    int gN   = (N + 255) / 256;
    int gE   = (E + 255) / 256;
    int gN16 = (N * 16 + 255) / 256;
    int gM   = (N + BM1 - 1) / BM1;
    int nb   = gN;

    auto align = [](size_t v) { return (v + 255) & ~(size_t)255; };
    char* w = (char*)d_ws;
    float* dinv   = (float*)w;  w += align((size_t)N * 4);
    int*   counts = (int*)w;    w += align((size_t)N * 4);
    int*   rowst  = (int*)w;    w += align((size_t)(N + 1) * 4);
    int*   bsum   = (int*)w;    w += align((size_t)nb * 4);
    int*   boff   = (int*)w;    w += align((size_t)nb * 4);
    int*   csr_src= (int*)w;    w += align((size_t)E * 4);
    float* csr_w  = (float*)w;  w += align((size_t)E * 4);
    __bf16* bufA  = (__bf16*)w; w += align((size_t)N * HID * 2);   // h1 then h2lin
    __bf16* bufB  = (__bf16*)w; w += align((size_t)N * HID * 2);   // x2
    __bf16* bufC  = (__bf16*)w; w += align((size_t)N * HID * 2);   // conv2 pre-relu
    float* rb2    = (float*)w;  w += align((size_t)B * HID * 4);
    int*   segs   = (int*)w;    w += align((size_t)(B + 1) * 4);
    __bf16* w1img = (__bf16*)w; w += align((size_t)64 * K1 * 2);
    __bf16* w2img = (__bf16*)w; w += align((size_t)64 * 64 * 2);
    float* part   = (float*)w;  w += align((size_t)B * MCH * 64 * 4);

    // ---- CSR build + dinv + prep ----
    hipMemsetAsync(counts, 0, (size_t)N * 4, stream);
    count_edges<<<gE, 256, 0, stream>>>(ei, counts, E);
    block_sums_dinv<<<gN, 256, 0, stream>>>(counts, bsum, dinv, N);
    scan_and_segs<<<2, 512, 0, stream>>>(bsum, boff, nb, batch, segs, N, B);
    write_rowstart<<<gN, 256, 0, stream>>>(counts, boff, rowst, N, E);
    scatter_csr<<<gE, 256, 0, stream>>>(ei, rowst, dinv, counts, csr_src, csr_w, E);
    prep_w<<<(64 * K1 + 64 * 64 + 255) / 256, 256, 0, stream>>>(W1, W2, w1img, w2img);
    rb2_k<<<B, 64, 0, stream>>>(x, xda, root, W2, rb2);

    // ---- layer 1 ----
    gemm1_mfma<<<gM, 256, 0, stream>>>(x, xda, w1img, bufA, N);
    gather<<<gN16, 256, 0, stream>>>(rowst, csr_src, csr_w, bufA, dinv, b1, bufB, N);  // bufB = x2

    // ---- layer 2 ----
    gemm2_mfma<<<gM, 256, 0, stream>>>(bufB, w2img, rb2, batch, bufA, N);              // bufA = h2lin
    gather<<<gN16, 256, 0, stream>>>(rowst, csr_src, csr_w, bufA, dinv, b2, bufC, N);

    // ---- readout ----
    mean_part<<<B * MCH, 256, 0, stream>>>(bufC, segs, part);
    mean_fin<<<B, 128, 0, stream>>>(part, bufB, segs, root, out);
}

// Round 8
// 239.455 us; speedup vs baseline: 1.2157x; 1.2157x over previous
//
#include <hip/hip_runtime.h>

#define IN1 128
#define K1 256
#define HID 64
#define MCH 16    // mean-reduction chunks per graph

typedef __attribute__((ext_vector_type(8))) __bf16 bf16x8;
typedef __attribute__((ext_vector_type(4))) __bf16 bf16x4;
typedef __attribute__((ext_vector_type(8))) unsigned short u16x8;
typedef __attribute__((ext_vector_type(4))) float f32x4;

// swizzled element index: XOR row-low-bits into 16B-slot bits
__device__ __forceinline__ int swz(int row, int k, int ldk) {
    return (row * ldk + k) ^ ((row & 7) << 3);
}

// ---------------- CSR build ----------------
__global__ __launch_bounds__(256) void count_edges(const int* __restrict__ ei, int* counts, int E) {
    int e = blockIdx.x * 256 + threadIdx.x;
    if (e < E) atomicAdd(&counts[ei[E + e]], 1);
}

__global__ __launch_bounds__(256) void block_sums_dinv(const int* __restrict__ counts,
                                                       int* __restrict__ bsum,
                                                       float* __restrict__ dinv, int N) {
    __shared__ int sh[256];
    int i = blockIdx.x * 256 + threadIdx.x;
    int v = (i < N) ? counts[i] : 0;
    if (i < N) dinv[i] = rsqrtf((float)v + 1.0f);
    sh[threadIdx.x] = v;
    __syncthreads();
    for (int off = 128; off > 0; off >>= 1) {
        if (threadIdx.x < off) sh[threadIdx.x] += sh[threadIdx.x + off];
        __syncthreads();
    }
    if (threadIdx.x == 0) bsum[blockIdx.x] = sh[0];
}

__global__ __launch_bounds__(512) void scan_and_segs(const int* __restrict__ bsum,
                                                     int* __restrict__ boff, int nb,
                                                     const int* __restrict__ batch,
                                                     int* __restrict__ segs, int N, int B) {
    if (blockIdx.x == 0) {
        __shared__ int sh[512];
        int t = threadIdx.x;
        int v = (t < nb) ? bsum[t] : 0;
        sh[t] = v;
        __syncthreads();
        for (int off = 1; off < 512; off <<= 1) {
            int u = (t >= off) ? sh[t - off] : 0;
            __syncthreads();
            sh[t] += u;
            __syncthreads();
        }
        if (t < nb) boff[t] = sh[t] - v;
    } else {
        int b = threadIdx.x;
        if (b > B) return;
        if (b == B) { segs[B] = N; return; }
        int lo = 0, hi = N;
        while (lo < hi) {
            int mid = (lo + hi) >> 1;
            if (batch[mid] < b) lo = mid + 1; else hi = mid;
        }
        segs[b] = lo;
    }
}

__global__ __launch_bounds__(256) void write_rowstart(const int* __restrict__ counts,
                                                      const int* __restrict__ boff,
                                                      int* __restrict__ rowstart, int N, int E) {
    __shared__ int sh[256];
    int i = blockIdx.x * 256 + threadIdx.x;
    int t = threadIdx.x;
    int v = (i < N) ? counts[i] : 0;
    sh[t] = v;
    __syncthreads();
    for (int off = 1; off < 256; off <<= 1) {
        int u = (t >= off) ? sh[t - off] : 0;
        __syncthreads();
        sh[t] += u;
        __syncthreads();
    }
    if (i < N) rowstart[i] = boff[blockIdx.x] + sh[t] - v;
    if (i == 0) rowstart[N] = E;
}

__global__ __launch_bounds__(256) void scatter_csr(const int* __restrict__ ei,
                                                   const int* __restrict__ rowstart,
                                                   const float* __restrict__ dinv,
                                                   int* counts,
                                                   int* __restrict__ csr_src,
                                                   float* __restrict__ csr_w, int E) {
    int e = blockIdx.x * 256 + threadIdx.x;
    if (e >= E) return;
    int s = ei[e], d = ei[E + e];
    int pos = rowstart[d] + atomicSub(&counts[d], 1) - 1;
    csr_src[pos] = s;
    csr_w[pos] = dinv[s];
}

// ---------------- W prep: bf16, transposed, pre-swizzled images ----------------
__global__ __launch_bounds__(256) void prep_w(const float* __restrict__ W1,
                                              const float* __restrict__ W2,
                                              __bf16* __restrict__ w1img,
                                              __bf16* __restrict__ w2img) {
    int tid = blockIdx.x * 256 + threadIdx.x;
    if (tid < 64 * K1) {
        int k = tid >> 6, n = tid & 63;
        w1img[swz(n, k, K1)] = (__bf16)W1[tid];
    } else if (tid < 64 * K1 + 64 * 64) {
        int e = tid - 64 * K1;
        int k = e >> 6, n = e & 63;
        w2img[swz(n, k, 64)] = (__bf16)W2[e];
    }
}

// ---------------- MFMA GEMM 1: h1 = bf16(concat(x,xda) @ W1) ----------------
// 64 rows/block, 4 waves (16 rows each); depth-4 rotating A-load pipeline.
// Tail rows handled by address clamp (M-rows independent in MFMA; store guarded).
__global__ __launch_bounds__(256, 4) void gemm1_mfma(const float* __restrict__ x,
                                                     const float* __restrict__ xda,
                                                     const __bf16* __restrict__ w1img,
                                                     __bf16* __restrict__ h1, int N) {
    __shared__ __bf16 Ws[64 * K1];   // 32 KB
    int tid = threadIdx.x;
#pragma unroll
    for (int i = 0; i < 8; ++i)
        reinterpret_cast<bf16x8*>(Ws)[i * 256 + tid] =
            reinterpret_cast<const bf16x8*>(w1img)[i * 256 + tid];
    __syncthreads();

    int w = tid >> 6, l = tid & 63;
    int lr = l & 15, lg = l >> 4;
    int arow = blockIdx.x * 64 + w * 16 + lr;
    int carow = min(arow, N - 1);                 // clamp: safe, never stored
    const float4* px = reinterpret_cast<const float4*>(x + (size_t)carow * IN1) + lg * 2;
    const float4* pd = reinterpret_cast<const float4*>(xda + (size_t)carow * IN1) + lg * 2;

    f32x4 acc[4] = {};
    float4 buf[4][2];   // depth-4 pipeline, statically indexed under full unroll

#pragma unroll
    for (int t = 0; t < 4; ++t) {     // preload t=0..3
        const float4* p = (t < 4) ? (px + t * 8) : (pd + (t - 4) * 8);
        buf[t][0] = p[0];
        buf[t][1] = p[1];
    }
#pragma unroll
    for (int t = 0; t < 8; ++t) {
        float4 fa = buf[t & 3][0], fb = buf[t & 3][1];
        if (t + 4 < 8) {              // refill freed slot with t+4
            int tn = t + 4;
            const float4* p = (tn < 4) ? (px + tn * 8) : (pd + (tn - 4) * 8);
            buf[t & 3][0] = p[0];
            buf[t & 3][1] = p[1];
        }
        bf16x8 af;
        af[0] = (__bf16)fa.x; af[1] = (__bf16)fa.y;
        af[2] = (__bf16)fa.z; af[3] = (__bf16)fa.w;
        af[4] = (__bf16)fb.x; af[5] = (__bf16)fb.y;
        af[6] = (__bf16)fb.z; af[7] = (__bf16)fb.w;
        int k0 = t * 32 + lg * 8;
#pragma unroll
        for (int c = 0; c < 4; ++c) {
            bf16x8 bfr = *reinterpret_cast<const bf16x8*>(&Ws[swz(c * 16 + lr, k0, K1)]);
            acc[c] = __builtin_amdgcn_mfma_f32_16x16x32_bf16(af, bfr, acc[c], 0, 0, 0);
        }
    }
    // C layout: col = lane&15, row = (lane>>4)*4 + reg
#pragma unroll
    for (int c = 0; c < 4; ++c)
#pragma unroll
        for (int r = 0; r < 4; ++r) {
            int row = blockIdx.x * 64 + w * 16 + lg * 4 + r;
            if (row < N) h1[(size_t)row * HID + c * 16 + lr] = (__bf16)acc[c][r];
        }
}

// ---------------- MFMA GEMM 2: h2 = bf16(relu(x2) @ W2[0:64] + rb2[batch]) ----------------
__global__ __launch_bounds__(256, 4) void gemm2_mfma(const __bf16* __restrict__ x2,
                                                     const __bf16* __restrict__ w2img,
                                                     const float* __restrict__ rb2,
                                                     const int* __restrict__ batch,
                                                     __bf16* __restrict__ h2, int N) {
    __shared__ __bf16 Ws[64 * 64];   // 8 KB
    int tid = threadIdx.x;
#pragma unroll
    for (int i = 0; i < 2; ++i)
        reinterpret_cast<bf16x8*>(Ws)[i * 256 + tid] =
            reinterpret_cast<const bf16x8*>(w2img)[i * 256 + tid];
    __syncthreads();

    int w = tid >> 6, l = tid & 63;
    int lr = l & 15, lg = l >> 4;
    int arow = blockIdx.x * 64 + w * 16 + lr;
    int carow = min(arow, N - 1);
    const u16x8* pa = reinterpret_cast<const u16x8*>(x2 + (size_t)carow * HID + lg * 8);

    // hoist both k-chunk loads (k0 = lg*8 and 32 + lg*8)
    u16x8 raw0 = pa[0];
    u16x8 raw1 = pa[2];   // +32 bf16 = +2 u16x8
    f32x4 acc[4] = {};
#pragma unroll
    for (int t = 0; t < 2; ++t) {
        u16x8 raw = t ? raw1 : raw0;
        u16x8 rel;
#pragma unroll
        for (int i = 0; i < 8; ++i)
            rel[i] = (raw[i] & 0x8000) ? (unsigned short)0 : raw[i];   // relu on bf16
        bf16x8 af = *reinterpret_cast<bf16x8*>(&rel);
        int k0 = t * 32 + lg * 8;
#pragma unroll
        for (int c = 0; c < 4; ++c) {
            bf16x8 bfr = *reinterpret_cast<const bf16x8*>(&Ws[swz(c * 16 + lr, k0, 64)]);
            acc[c] = __builtin_amdgcn_mfma_f32_16x16x32_bf16(af, bfr, acc[c], 0, 0, 0);
        }
    }
#pragma unroll
    for (int r = 0; r < 4; ++r) {
        int row = blockIdx.x * 64 + w * 16 + lg * 4 + r;
        if (row >= N) continue;
        int b = batch[row];
        const float* rv = rb2 + (size_t)b * HID;
#pragma unroll
        for (int c = 0; c < 4; ++c)
            h2[(size_t)row * HID + c * 16 + lr] = (__bf16)(acc[c][r] + rv[c * 16 + lr]);
    }
}

// ---------------- gather: out = bf16( h*dinv^2 + bias + sum_e h[src]*w*dinv ) ----------------
__global__ __launch_bounds__(256) void gather(const int* __restrict__ rowstart,
                                              const int* __restrict__ csr_src,
                                              const float* __restrict__ csr_w,
                                              const __bf16* __restrict__ h,
                                              const float* __restrict__ dinv,
                                              const float* __restrict__ bias,
                                              __bf16* __restrict__ out, int N) {
    int t = blockIdx.x * 256 + threadIdx.x;
    int i = t >> 4, c = t & 15;
    if (i >= N) return;
    float di = dinv[i];
    float s2 = di * di;
    bf16x4 hv = *reinterpret_cast<const bf16x4*>(h + (size_t)i * HID + c * 4);
    float4 bv = reinterpret_cast<const float4*>(bias)[c];
    float a0 = fmaf((float)hv[0], s2, bv.x);
    float a1 = fmaf((float)hv[1], s2, bv.y);
    float a2 = fmaf((float)hv[2], s2, bv.z);
    float a3 = fmaf((float)hv[3], s2, bv.w);
    int k0 = rowstart[i], k1 = rowstart[i + 1];
    for (int k = k0; k < k1; ++k) {
        int s = csr_src[k];
        float wgt = csr_w[k] * di;
        bf16x4 sv = *reinterpret_cast<const bf16x4*>(h + (size_t)s * HID + c * 4);
        a0 = fmaf((float)sv[0], wgt, a0);
        a1 = fmaf((float)sv[1], wgt, a1);
        a2 = fmaf((float)sv[2], wgt, a2);
        a3 = fmaf((float)sv[3], wgt, a3);
    }
    bf16x4 o;
    o[0] = (__bf16)a0; o[1] = (__bf16)a1; o[2] = (__bf16)a2; o[3] = (__bf16)a3;
    *reinterpret_cast<bf16x4*>(out + (size_t)i * HID + c * 4) = o;
}

// rb2[b][j] = sum_k relu(x0[root_b][k]) * W2[64+k][j]   (fp32)
__global__ __launch_bounds__(64) void rb2_k(const float* __restrict__ x,
                                            const float* __restrict__ xda,
                                            const int* __restrict__ rootindex,
                                            const float* __restrict__ W2,
                                            float* __restrict__ rb2) {
    int b = blockIdx.x;
    int j = threadIdx.x;
    int root = rootindex[b];
    const float* xr = x + (size_t)root * IN1;
    const float* dr = xda + (size_t)root * IN1;
    float acc = 0.f;
    for (int k = 0; k < IN1; ++k) {
        float v = fmaxf(xr[k], 0.f);
        acc = fmaf(v, W2[(size_t)(HID + k) * HID + j], acc);
    }
    for (int k = 0; k < IN1; ++k) {
        float v = fmaxf(dr[k], 0.f);
        acc = fmaf(v, W2[(size_t)(HID + IN1 + k) * HID + j], acc);
    }
    rb2[b * HID + j] = acc;
}

// ---------------- mean: two-stage ----------------
__global__ __launch_bounds__(256) void mean_part(const __bf16* __restrict__ agg2,
                                                 const int* __restrict__ segs,
                                                 float* __restrict__ part) {
    int b = blockIdx.x / MCH, c = blockIdx.x % MCH;
    int s = segs[b], e = segs[b + 1];
    long len = e - s;
    int cs = s + (int)(len * c / MCH);
    int ce = s + (int)(len * (c + 1) / MCH);
    int f = threadIdx.x & 63, g = threadIdx.x >> 6;
    float p = 0.f;
    for (int i = cs + g; i < ce; i += 4)
        p += fmaxf((float)agg2[(size_t)i * HID + f], 0.f);
    __shared__ float red[4][64];
    red[g][f] = p;
    __syncthreads();
    if (g == 0)
        part[((size_t)b * MCH + c) * 64 + f] = red[0][f] + red[1][f] + red[2][f] + red[3][f];
}

__global__ __launch_bounds__(128) void mean_fin(const float* __restrict__ part,
                                                const __bf16* __restrict__ x2,
                                                const int* __restrict__ segs,
                                                const int* __restrict__ rootindex,
                                                float* __restrict__ out) {
    int b = blockIdx.x;
    int f = threadIdx.x;   // 0..127
    if (f < 64) {
        float s = 0.f;
#pragma unroll
        for (int c = 0; c < MCH; ++c) s += part[((size_t)b * MCH + c) * 64 + f];
        out[b * 128 + f] = s / (float)(segs[b + 1] - segs[b]);
    } else {
        int root = rootindex[b];
        out[b * 128 + f] = (float)x2[(size_t)root * HID + (f - 64)];
    }
}

extern "C" void kernel_launch(void* const* d_in, const int* in_sizes, int n_in,
                              void* d_out, int out_size, void* d_ws, size_t ws_size,
                              hipStream_t stream) {
    const float* x    = (const float*)d_in[0];
    const float* xda  = (const float*)d_in[1];
    const int*   ei   = (const int*)d_in[2];
    const int*   batch= (const int*)d_in[3];
    const int*   root = (const int*)d_in[4];
    const float* W1   = (const float*)d_in[5];
    const float* b1   = (const float*)d_in[6];
    const float* W2   = (const float*)d_in[7];
    const float* b2   = (const float*)d_in[8];
    float* out = (float*)d_out;

    int N = in_sizes[3];
    int E = in_sizes[2] / 2;
    int B = in_sizes[4];

    int gN   = (N + 255) / 256;
    int gE   = (E + 255) / 256;
    int gN16 = (N * 16 + 255) / 256;
    int gM   = (N + 63) / 64;
    int nb   = gN;

    auto align = [](size_t v) { return (v + 255) & ~(size_t)255; };
    char* w = (char*)d_ws;
    float* dinv   = (float*)w;  w += align((size_t)N * 4);
    int*   counts = (int*)w;    w += align((size_t)N * 4);
    int*   rowst  = (int*)w;    w += align((size_t)(N + 1) * 4);
    int*   bsum   = (int*)w;    w += align((size_t)nb * 4);
    int*   boff   = (int*)w;    w += align((size_t)nb * 4);
    int*   csr_src= (int*)w;    w += align((size_t)E * 4);
    float* csr_w  = (float*)w;  w += align((size_t)E * 4);
    __bf16* bufA  = (__bf16*)w; w += align((size_t)N * HID * 2);   // h1 then h2lin
    __bf16* bufB  = (__bf16*)w; w += align((size_t)N * HID * 2);   // x2
    __bf16* bufC  = (__bf16*)w; w += align((size_t)N * HID * 2);   // conv2 pre-relu
    float* rb2    = (float*)w;  w += align((size_t)B * HID * 4);
    int*   segs   = (int*)w;    w += align((size_t)(B + 1) * 4);
    __bf16* w1img = (__bf16*)w; w += align((size_t)64 * K1 * 2);
    __bf16* w2img = (__bf16*)w; w += align((size_t)64 * 64 * 2);
    float* part   = (float*)w;  w += align((size_t)B * MCH * 64 * 4);

    // ---- CSR build + dinv + prep ----
    hipMemsetAsync(counts, 0, (size_t)N * 4, stream);
    count_edges<<<gE, 256, 0, stream>>>(ei, counts, E);
    block_sums_dinv<<<gN, 256, 0, stream>>>(counts, bsum, dinv, N);
    scan_and_segs<<<2, 512, 0, stream>>>(bsum, boff, nb, batch, segs, N, B);
    write_rowstart<<<gN, 256, 0, stream>>>(counts, boff, rowst, N, E);
    scatter_csr<<<gE, 256, 0, stream>>>(ei, rowst, dinv, counts, csr_src, csr_w, E);
    prep_w<<<(64 * K1 + 64 * 64 + 255) / 256, 256, 0, stream>>>(W1, W2, w1img, w2img);
    rb2_k<<<B, 64, 0, stream>>>(x, xda, root, W2, rb2);

    // ---- layer 1 ----
    gemm1_mfma<<<gM, 256, 0, stream>>>(x, xda, w1img, bufA, N);
    gather<<<gN16, 256, 0, stream>>>(rowst, csr_src, csr_w, bufA, dinv, b1, bufB, N);  // bufB = x2

    // ---- layer 2 ----
    gemm2_mfma<<<gM, 256, 0, stream>>>(bufB, w2img, rb2, batch, bufA, N);              // bufA = h2lin
    gather<<<gN16, 256, 0, stream>>>(rowst, csr_src, csr_w, bufA, dinv, b2, bufC, N);

    // ---- readout ----
    mean_part<<<B * MCH, 256, 0, stream>>>(bufC, segs, part);
    mean_fin<<<B, 128, 0, stream>>>(part, bufB, segs, root, out);
}

// Round 11
// 235.906 us; speedup vs baseline: 1.2340x; 1.0150x over previous
//
#include <hip/hip_runtime.h>

#define IN1 128
#define K1 256
#define HID 64

typedef __attribute__((ext_vector_type(8))) __bf16 bf16x8;
typedef __attribute__((ext_vector_type(4))) __bf16 bf16x4;
typedef __attribute__((ext_vector_type(4))) float f32x4;

// swizzled element index: XOR row-low-bits into 16B-slot bits
__device__ __forceinline__ int swz(int row, int k, int ldk) {
    return (row * ldk + k) ^ ((row & 7) << 3);
}

// ---------------- CSR build ----------------
__global__ __launch_bounds__(256) void count_edges(const int* __restrict__ ei, int* counts, int E) {
    int e = blockIdx.x * 256 + threadIdx.x;
    if (e < E) atomicAdd(&counts[ei[E + e]], 1);
}

__global__ __launch_bounds__(256) void block_sums_dinv(const int* __restrict__ counts,
                                                       int* __restrict__ bsum,
                                                       float* __restrict__ dinv, int N) {
    __shared__ int sh[256];
    int i = blockIdx.x * 256 + threadIdx.x;
    int v = (i < N) ? counts[i] : 0;
    if (i < N) dinv[i] = rsqrtf((float)v + 1.0f);
    sh[threadIdx.x] = v;
    __syncthreads();
    for (int off = 128; off > 0; off >>= 1) {
        if (threadIdx.x < off) sh[threadIdx.x] += sh[threadIdx.x + off];
        __syncthreads();
    }
    if (threadIdx.x == 0) bsum[blockIdx.x] = sh[0];
}

__global__ __launch_bounds__(512) void scan_and_segs(const int* __restrict__ bsum,
                                                     int* __restrict__ boff, int nb,
                                                     const int* __restrict__ batch,
                                                     int* __restrict__ segs, int N, int B) {
    if (blockIdx.x == 0) {
        __shared__ int sh[512];
        int t = threadIdx.x;
        int v = (t < nb) ? bsum[t] : 0;
        sh[t] = v;
        __syncthreads();
        for (int off = 1; off < 512; off <<= 1) {
            int u = (t >= off) ? sh[t - off] : 0;
            __syncthreads();
            sh[t] += u;
            __syncthreads();
        }
        if (t < nb) boff[t] = sh[t] - v;
    } else {
        int b = threadIdx.x;
        if (b > B) return;
        if (b == B) { segs[B] = N; return; }
        int lo = 0, hi = N;
        while (lo < hi) {
            int mid = (lo + hi) >> 1;
            if (batch[mid] < b) lo = mid + 1; else hi = mid;
        }
        segs[b] = lo;
    }
}

__global__ __launch_bounds__(256) void write_rowstart(const int* __restrict__ counts,
                                                      const int* __restrict__ boff,
                                                      int* __restrict__ rowstart, int N, int E) {
    __shared__ int sh[256];
    int i = blockIdx.x * 256 + threadIdx.x;
    int t = threadIdx.x;
    int v = (i < N) ? counts[i] : 0;
    sh[t] = v;
    __syncthreads();
    for (int off = 1; off < 256; off <<= 1) {
        int u = (t >= off) ? sh[t - off] : 0;
        __syncthreads();
        sh[t] += u;
        __syncthreads();
    }
    if (i < N) rowstart[i] = boff[blockIdx.x] + sh[t] - v;
    if (i == 0) rowstart[N] = E;
}

__global__ __launch_bounds__(256) void scatter_csr(const int* __restrict__ ei,
                                                   const int* __restrict__ rowstart,
                                                   const float* __restrict__ dinv,
                                                   int* counts,
                                                   int* __restrict__ csr_src,
                                                   float* __restrict__ csr_w, int E) {
    int e = blockIdx.x * 256 + threadIdx.x;
    if (e >= E) return;
    int s = ei[e], d = ei[E + e];
    int pos = rowstart[d] + atomicSub(&counts[d], 1) - 1;
    csr_src[pos] = s;
    csr_w[pos] = dinv[s];
}

// ---------------- prep: W images (blocks 0..79) + rb2 (blocks 80..80+B-1) ----------------
__global__ __launch_bounds__(256) void prep_fused(const float* __restrict__ W1,
                                                  const float* __restrict__ W2,
                                                  __bf16* __restrict__ w1img,
                                                  __bf16* __restrict__ w2img,
                                                  const float* __restrict__ x,
                                                  const float* __restrict__ xda,
                                                  const int* __restrict__ rootindex,
                                                  float* __restrict__ rb2) {
    int blk = blockIdx.x;
    if (blk < 80) {
        int tid = blk * 256 + threadIdx.x;
        if (tid < 64 * K1) {
            int k = tid >> 6, n = tid & 63;
            w1img[swz(n, k, K1)] = (__bf16)W1[tid];
        } else if (tid < 64 * K1 + 64 * 64) {
            int e = tid - 64 * K1;
            int k = e >> 6, n = e & 63;
            w2img[swz(n, k, 64)] = (__bf16)W2[e];
        }
    } else {
        int b = blk - 80;
        int root = rootindex[b];
        int j = threadIdx.x & 63, q = threadIdx.x >> 6;
        const float* xr = x + (size_t)root * IN1;
        const float* dr = xda + (size_t)root * IN1;
        float acc = 0.f;
        for (int kk = 0; kk < 64; ++kk) {
            int k = q * 64 + kk;
            float v = (k < IN1) ? xr[k] : dr[k - IN1];
            v = fmaxf(v, 0.f);
            acc = fmaf(v, W2[(size_t)(HID + k) * HID + j], acc);
        }
        __shared__ float sh[4][64];
        sh[q][j] = acc;
        __syncthreads();
        if (q == 0) rb2[b * HID + j] = sh[0][j] + sh[1][j] + sh[2][j] + sh[3][j];
    }
}

// ---------------- MFMA GEMM 1: h1 = bf16(concat(x,xda) @ W1) ----------------
__global__ __launch_bounds__(256, 4) void gemm1_mfma(const float* __restrict__ x,
                                                     const float* __restrict__ xda,
                                                     const __bf16* __restrict__ w1img,
                                                     __bf16* __restrict__ h1, int N) {
    __shared__ __bf16 Ws[64 * K1];   // 32 KB
    int tid = threadIdx.x;
#pragma unroll
    for (int i = 0; i < 8; ++i)
        reinterpret_cast<bf16x8*>(Ws)[i * 256 + tid] =
            reinterpret_cast<const bf16x8*>(w1img)[i * 256 + tid];
    __syncthreads();

    int w = tid >> 6, l = tid & 63;
    int lr = l & 15, lg = l >> 4;
    int arow = blockIdx.x * 64 + w * 16 + lr;
    int carow = min(arow, N - 1);
    const float4* px = reinterpret_cast<const float4*>(x + (size_t)carow * IN1) + lg * 2;
    const float4* pd = reinterpret_cast<const float4*>(xda + (size_t)carow * IN1) + lg * 2;

    f32x4 acc[4] = {};
    float4 buf[4][2];

#pragma unroll
    for (int t = 0; t < 4; ++t) {
        const float4* p = px + t * 8;
        buf[t][0] = p[0];
        buf[t][1] = p[1];
    }
#pragma unroll
    for (int t = 0; t < 8; ++t) {
        float4 fa = buf[t & 3][0], fb = buf[t & 3][1];
        if (t + 4 < 8) {
            int tn = t + 4;
            const float4* p = pd + (tn - 4) * 8;
            buf[t & 3][0] = p[0];
            buf[t & 3][1] = p[1];
        }
        bf16x8 af;
        af[0] = (__bf16)fa.x; af[1] = (__bf16)fa.y;
        af[2] = (__bf16)fa.z; af[3] = (__bf16)fa.w;
        af[4] = (__bf16)fb.x; af[5] = (__bf16)fb.y;
        af[6] = (__bf16)fb.z; af[7] = (__bf16)fb.w;
        int k0 = t * 32 + lg * 8;
#pragma unroll
        for (int c = 0; c < 4; ++c) {
            bf16x8 bfr = *reinterpret_cast<const bf16x8*>(&Ws[swz(c * 16 + lr, k0, K1)]);
            acc[c] = __builtin_amdgcn_mfma_f32_16x16x32_bf16(af, bfr, acc[c], 0, 0, 0);
        }
    }
#pragma unroll
    for (int c = 0; c < 4; ++c)
#pragma unroll
        for (int r = 0; r < 4; ++r) {
            int row = blockIdx.x * 64 + w * 16 + lg * 4 + r;
            if (row < N) h1[(size_t)row * HID + c * 16 + lr] = (__bf16)acc[c][r];
        }
}

// ---------------- conv2_fused: x2 = gather(h1)+b1; h2 = bf16(relu(x2)@W2[:64] + rb2) ----------------
// 1024 threads / 64 nodes. Root detection via binary search on sorted rootindex
// (rootindex[b] = floor(b*N/B) may lie OUTSIDE segment b — no membership assumption).
__global__ __launch_bounds__(1024, 4) void conv2_fused(const int* __restrict__ rowstart,
                                                       const int* __restrict__ csr_src,
                                                       const float* __restrict__ csr_w,
                                                       const __bf16* __restrict__ h1,
                                                       const float* __restrict__ dinv,
                                                       const float* __restrict__ bias1,
                                                       const __bf16* __restrict__ w2img,
                                                       const float* __restrict__ rb2,
                                                       const int* __restrict__ batch,
                                                       const int* __restrict__ rootindex,
                                                       __bf16* __restrict__ h2,
                                                       float* __restrict__ rootx2, int N, int B) {
    __shared__ __bf16 As[64 * 64];   // 8 KB, swizzled relu(x2)
    __shared__ __bf16 Ws[64 * 64];   // 8 KB
    int tid = threadIdx.x;
    if (tid < 512)
        reinterpret_cast<bf16x8*>(Ws)[tid] = reinterpret_cast<const bf16x8*>(w2img)[tid];

    int nb0 = blockIdx.x * 64;
    int ln = tid >> 4, cq = tid & 15;
    int i = nb0 + ln;
    bool ok = i < N;
    int ci = ok ? i : N - 1;
    float di = dinv[ci];
    float s2 = di * di;
    bf16x4 hv = *reinterpret_cast<const bf16x4*>(h1 + (size_t)ci * HID + cq * 4);
    float4 bv = reinterpret_cast<const float4*>(bias1)[cq];
    float a0 = fmaf((float)hv[0], s2, bv.x);
    float a1 = fmaf((float)hv[1], s2, bv.y);
    float a2 = fmaf((float)hv[2], s2, bv.z);
    float a3 = fmaf((float)hv[3], s2, bv.w);
    int k0 = rowstart[ci], k1 = rowstart[ci + 1];
    for (int k = k0; k < k1; ++k) {
        int s = csr_src[k];
        float wgt = csr_w[k] * di;
        bf16x4 sv = *reinterpret_cast<const bf16x4*>(h1 + (size_t)s * HID + cq * 4);
        a0 = fmaf((float)sv[0], wgt, a0);
        a1 = fmaf((float)sv[1], wgt, a1);
        a2 = fmaf((float)sv[2], wgt, a2);
        a3 = fmaf((float)sv[3], wgt, a3);
    }
    // Is node i the root of SOME graph? (rootindex strictly increasing since N > B)
    if (ok) {
        int lo = 0, hi = B - 1, bfound = -1;
        while (lo <= hi) {
            int mid = (lo + hi) >> 1;
            int rv = rootindex[mid];
            if (rv == i) { bfound = mid; break; }
            if (rv < i) lo = mid + 1; else hi = mid - 1;
        }
        if (bfound >= 0) {
            float4 o = make_float4(a0, a1, a2, a3);
            reinterpret_cast<float4*>(rootx2 + (size_t)bfound * 64)[cq] = o;
        }
    }
    // relu -> swizzled LDS (bf16)
    bf16x4 rl;
    rl[0] = (__bf16)fmaxf(a0, 0.f); rl[1] = (__bf16)fmaxf(a1, 0.f);
    rl[2] = (__bf16)fmaxf(a2, 0.f); rl[3] = (__bf16)fmaxf(a3, 0.f);
    *reinterpret_cast<bf16x4*>(&As[swz(ln, cq * 4, 64)]) = rl;
    __syncthreads();

    // MFMA: wave w -> row-group rg, col-block cb
    int w = tid >> 6;
    int rg = w >> 2, cb = w & 3;
    int l = tid & 63, lr = l & 15, lg = l >> 4;
    f32x4 acc = {};
#pragma unroll
    for (int t = 0; t < 2; ++t) {
        int kk = t * 32 + lg * 8;
        bf16x8 af = *reinterpret_cast<const bf16x8*>(&As[swz(rg * 16 + lr, kk, 64)]);
        bf16x8 bfr = *reinterpret_cast<const bf16x8*>(&Ws[swz(cb * 16 + lr, kk, 64)]);
        acc = __builtin_amdgcn_mfma_f32_16x16x32_bf16(af, bfr, acc, 0, 0, 0);
    }
#pragma unroll
    for (int r = 0; r < 4; ++r) {
        int row = nb0 + rg * 16 + lg * 4 + r;
        if (row >= N) continue;
        int b = batch[row];
        h2[(size_t)row * HID + cb * 16 + lr] =
            (__bf16)(acc[r] + rb2[(size_t)b * HID + cb * 16 + lr]);
    }
}

// ---------------- conv3_mean: agg2 = gather(h2)+b2; relu; segment-sum into part ----------------
__global__ __launch_bounds__(1024, 4) void conv3_mean(const int* __restrict__ rowstart,
                                                      const int* __restrict__ csr_src,
                                                      const float* __restrict__ csr_w,
                                                      const __bf16* __restrict__ h2,
                                                      const float* __restrict__ dinv,
                                                      const float* __restrict__ bias2,
                                                      const int* __restrict__ batch,
                                                      float* __restrict__ part, int N) {
    __shared__ float red[64][64];   // 16 KB
    int tid = threadIdx.x;
    int nb0 = blockIdx.x * 64;
    int ln = tid >> 4, cq = tid & 15;
    int i = nb0 + ln;
    bool ok = i < N;
    int ci = ok ? i : N - 1;
    float di = dinv[ci];
    float s2 = di * di;
    bf16x4 hv = *reinterpret_cast<const bf16x4*>(h2 + (size_t)ci * HID + cq * 4);
    float4 bv = reinterpret_cast<const float4*>(bias2)[cq];
    float a0 = fmaf((float)hv[0], s2, bv.x);
    float a1 = fmaf((float)hv[1], s2, bv.y);
    float a2 = fmaf((float)hv[2], s2, bv.z);
    float a3 = fmaf((float)hv[3], s2, bv.w);
    int k0 = rowstart[ci], k1 = rowstart[ci + 1];
    for (int k = k0; k < k1; ++k) {
        int s = csr_src[k];
        float wgt = csr_w[k] * di;
        bf16x4 sv = *reinterpret_cast<const bf16x4*>(h2 + (size_t)s * HID + cq * 4);
        a0 = fmaf((float)sv[0], wgt, a0);
        a1 = fmaf((float)sv[1], wgt, a1);
        a2 = fmaf((float)sv[2], wgt, a2);
        a3 = fmaf((float)sv[3], wgt, a3);
    }
    float v0 = fmaxf(a0, 0.f), v1 = fmaxf(a1, 0.f);
    float v2 = fmaxf(a2, 0.f), v3 = fmaxf(a3, 0.f);

    int gme = ok ? batch[i] : -1;
    int g0 = batch[nb0];
    int gLast = batch[min(nb0 + 63, N - 1)];
    int g = g0;
    while (true) {
        float m = (gme == g) ? 1.f : 0.f;
        int f = cq * 4;
        red[ln][f + 0] = v0 * m;
        red[ln][f + 1] = v1 * m;
        red[ln][f + 2] = v2 * m;
        red[ln][f + 3] = v3 * m;
        __syncthreads();
#pragma unroll
        for (int off = 32; off > 0; off >>= 1) {
            if (ln < off) {
                red[ln][f + 0] += red[ln + off][f + 0];
                red[ln][f + 1] += red[ln + off][f + 1];
                red[ln][f + 2] += red[ln + off][f + 2];
                red[ln][f + 3] += red[ln + off][f + 3];
            }
            __syncthreads();
        }
        if (ln == 0) {
            atomicAdd(&part[(size_t)g * 64 + f + 0], red[0][f + 0]);
            atomicAdd(&part[(size_t)g * 64 + f + 1], red[0][f + 1]);
            atomicAdd(&part[(size_t)g * 64 + f + 2], red[0][f + 2]);
            atomicAdd(&part[(size_t)g * 64 + f + 3], red[0][f + 3]);
        }
        if (g == gLast) break;
        g = gLast;
        __syncthreads();
    }
}

// ---------------- finalize: out = part/len || rootx2 ----------------
__global__ __launch_bounds__(128) void mean_fin(const float* __restrict__ part,
                                                const float* __restrict__ rootx2,
                                                const int* __restrict__ segs,
                                                float* __restrict__ out) {
    int b = blockIdx.x;
    int f = threadIdx.x;
    if (f < 64)
        out[b * 128 + f] = part[(size_t)b * 64 + f] / (float)(segs[b + 1] - segs[b]);
    else
        out[b * 128 + f] = rootx2[(size_t)b * 64 + (f - 64)];
}

extern "C" void kernel_launch(void* const* d_in, const int* in_sizes, int n_in,
                              void* d_out, int out_size, void* d_ws, size_t ws_size,
                              hipStream_t stream) {
    const float* x    = (const float*)d_in[0];
    const float* xda  = (const float*)d_in[1];
    const int*   ei   = (const int*)d_in[2];
    const int*   batch= (const int*)d_in[3];
    const int*   root = (const int*)d_in[4];
    const float* W1   = (const float*)d_in[5];
    const float* b1   = (const float*)d_in[6];
    const float* W2   = (const float*)d_in[7];
    const float* b2   = (const float*)d_in[8];
    float* out = (float*)d_out;

    int N = in_sizes[3];
    int E = in_sizes[2] / 2;
    int B = in_sizes[4];

    int gN  = (N + 255) / 256;
    int gE  = (E + 255) / 256;
    int gM  = (N + 63) / 64;
    int nb  = gN;

    auto align = [](size_t v) { return (v + 255) & ~(size_t)255; };
    char* w = (char*)d_ws;
    int*   counts = (int*)w;    w += align((size_t)N * 4);
    float* part   = (float*)w;  w += align((size_t)B * 64 * 4);    // adjacent to counts: one memset
    size_t zspan  = (char*)w - (char*)counts;
    float* dinv   = (float*)w;  w += align((size_t)N * 4);
    int*   rowst  = (int*)w;    w += align((size_t)(N + 1) * 4);
    int*   bsum   = (int*)w;    w += align((size_t)nb * 4);
    int*   boff   = (int*)w;    w += align((size_t)nb * 4);
    int*   csr_src= (int*)w;    w += align((size_t)E * 4);
    float* csr_w  = (float*)w;  w += align((size_t)E * 4);
    __bf16* bufA  = (__bf16*)w; w += align((size_t)N * HID * 2);   // h1
    __bf16* bufC  = (__bf16*)w; w += align((size_t)N * HID * 2);   // h2
    float* rootx2 = (float*)w;  w += align((size_t)B * 64 * 4);
    float* rb2    = (float*)w;  w += align((size_t)B * HID * 4);
    int*   segs   = (int*)w;    w += align((size_t)(B + 1) * 4);
    __bf16* w1img = (__bf16*)w; w += align((size_t)64 * K1 * 2);
    __bf16* w2img = (__bf16*)w; w += align((size_t)64 * 64 * 2);

    // ---- CSR build + prep ----
    hipMemsetAsync(counts, 0, zspan, stream);                      // counts + part
    count_edges<<<gE, 256, 0, stream>>>(ei, counts, E);
    block_sums_dinv<<<gN, 256, 0, stream>>>(counts, bsum, dinv, N);
    scan_and_segs<<<2, 512, 0, stream>>>(bsum, boff, nb, batch, segs, N, B);
    write_rowstart<<<gN, 256, 0, stream>>>(counts, boff, rowst, N, E);
    scatter_csr<<<gE, 256, 0, stream>>>(ei, rowst, dinv, counts, csr_src, csr_w, E);
    prep_fused<<<80 + B, 256, 0, stream>>>(W1, W2, w1img, w2img, x, xda, root, rb2);

    // ---- layer 1 GEMM ----
    gemm1_mfma<<<gM, 256, 0, stream>>>(x, xda, w1img, bufA, N);

    // ---- conv1-agg + relu + GEMM2 fused ----
    conv2_fused<<<gM, 1024, 0, stream>>>(rowst, csr_src, csr_w, bufA, dinv, b1,
                                         w2img, rb2, batch, root, bufC, rootx2, N, B);

    // ---- conv2-agg + relu + segment-mean fused ----
    conv3_mean<<<gM, 1024, 0, stream>>>(rowst, csr_src, csr_w, bufC, dinv, b2,
                                        batch, part, N);

    // ---- finalize ----
    mean_fin<<<B, 128, 0, stream>>>(part, rootx2, segs, out);
}